// Round 13
// baseline (162.186 us; speedup 1.0000x reference)
//
#include <hip/hip_runtime.h>
#include <hip/hip_bf16.h>

#define M_TOTAL 65536
#define DIM 768
#define KC 64
#define INV_T 10.0f

// k_weighted tiling
#define DT 128    // d-cols per block
#define MB 64     // m per LDS chunk
#define CH 8      // chunks per block (m-range 512)
#define MSEG 128  // m-segments (partials)

#define LOGITS_BLOCKS (M_TOTAL / 64)   // 1024 (64 rows per block)
#define SROWS 128
#define SINK_BLOCKS (M_TOTAL / SROWS)  // 512
#define PSG_ROWS 64                    // two-level PS: 64 group rows of 64 floats

typedef __attribute__((ext_vector_type(4))) float f32x4;
typedef __attribute__((ext_vector_type(8))) short bf16x8;
typedef __attribute__((ext_vector_type(4))) unsigned short u16x4;

__device__ __forceinline__ short f2bf(float f) {
    __hip_bfloat16 h = __float2bfloat16(f);
    union { __hip_bfloat16 h; short s; } u; u.h = h;
    return u.s;
}

// ---------------- K0: normalize centers -> cn + cnbf; zero PSG --------------------
__global__ __launch_bounds__(256) void k_centers(const float* __restrict__ centers,
                                                 float* __restrict__ cn,
                                                 short* __restrict__ cnbf,
                                                 float* __restrict__ psg) {
    int k = blockIdx.x, tid = threadIdx.x;
    psg[k * 256 + tid] = 0.f;  // 64*256 = 16384 = all four PSG arrays
    float ss = 0.f;
    for (int i = tid; i < DIM; i += 256) { float v = centers[k * DIM + i]; ss += v * v; }
    __shared__ float red[4];
    for (int o = 32; o; o >>= 1) ss += __shfl_xor(ss, o);
    if ((tid & 63) == 0) red[tid >> 6] = ss;
    __syncthreads();
    ss = red[0] + red[1] + red[2] + red[3];
    float inv = 1.0f / fmaxf(sqrtf(ss), 1e-12f);
    for (int i = tid; i < DIM; i += 256) {
        float v = centers[k * DIM + i] * inv;
        cn[k * DIM + i] = v;
        cnbf[k * DIM + i] = f2bf(v);
    }
}

// ---------------- K1: logits GEMM — wave-autonomous, barrier-free pipeline --------
// (unchanged from R12)
__global__ __launch_bounds__(256) void k_logits(const float* __restrict__ F,
                                                const short* __restrict__ cnbf,
                                                float* __restrict__ E,
                                                float* __restrict__ invn,
                                                float* __restrict__ PSG0) {
    __shared__ float fbuf[3][4][1024];  // [buf][wave][16 rows x 64 cols], 48 KiB
    __shared__ float bsr[4][KC];
    int tid = threadIdx.x;
    int wave = tid >> 6, lane = tid & 63;
    int l15 = lane & 15, lhi = lane >> 4;
    int rowbase = blockIdx.x * 64;

    int srow_l = lane >> 4;          // row within 4-row group
    int c4 = lane & 15;              // col granule (16B)

#define STAGE(t_, b_)                                                                     \
    do {                                                                                  \
        _Pragma("unroll") for (int i_ = 0; i_ < 4; ++i_) {                                \
            int r_ = i_ * 4 + srow_l;  /* local row 0..15 */                              \
            const float* src_ = F + (size_t)(rowbase + wave * 16 + r_) * DIM + (t_) * 64  \
                                + (((c4 ^ (r_ & 7)) << 2));                               \
            float* dst_ = &fbuf[b_][wave][i_ * 256];                                      \
            __builtin_amdgcn_global_load_lds(                                             \
                (const __attribute__((address_space(1))) void*)src_,                      \
                (__attribute__((address_space(3))) void*)dst_, 16, 0, 0);                 \
        }                                                                                 \
    } while (0)

    STAGE(0, 0);
    STAGE(1, 1);

    f32x4 acc[4];
#pragma unroll
    for (int n = 0; n < 4; ++n) acc[n] = (f32x4){0.f, 0.f, 0.f, 0.f};
    float ss = 0.f;

    const short* Bb = cnbf + (size_t)l15 * DIM + lhi * 8;
    int swz = (l15 & 7) << 2;

#pragma unroll
    for (int t = 0; t < 12; ++t) {
        bf16x8 b[8];
#pragma unroll
        for (int n = 0; n < 4; ++n) {
            b[n * 2]     = *(const bf16x8*)(Bb + (size_t)n * 16 * DIM + t * 64);
            b[n * 2 + 1] = *(const bf16x8*)(Bb + (size_t)n * 16 * DIM + t * 64 + 32);
        }
        if (t + 2 < 12) {
            STAGE(t + 2, (t + 2) % 3);
            asm volatile("s_waitcnt vmcnt(4)" ::: "memory");  // S(t)+B(t) done; S(t+2) in flight
        } else {
            asm volatile("s_waitcnt vmcnt(0)" ::: "memory");
        }
        __builtin_amdgcn_sched_barrier(0);
        const float* cb = &fbuf[t % 3][wave][l15 * 64];
#pragma unroll
        for (int kk = 0; kk < 2; ++kk) {
            int c0s = (kk * 32 + lhi * 8) ^ swz;
            f32x4 fa = *(const f32x4*)(cb + c0s);
            f32x4 fb2 = *(const f32x4*)(cb + (c0s ^ 4));
            ss += fa[0] * fa[0] + fa[1] * fa[1] + fa[2] * fa[2] + fa[3] * fa[3]
                + fb2[0] * fb2[0] + fb2[1] * fb2[1] + fb2[2] * fb2[2] + fb2[3] * fb2[3];
            bf16x8 af;
            af[0] = f2bf(fa[0]); af[1] = f2bf(fa[1]); af[2] = f2bf(fa[2]); af[3] = f2bf(fa[3]);
            af[4] = f2bf(fb2[0]); af[5] = f2bf(fb2[1]); af[6] = f2bf(fb2[2]); af[7] = f2bf(fb2[3]);
#pragma unroll
            for (int n = 0; n < 4; ++n)
                acc[n] = __builtin_amdgcn_mfma_f32_16x16x32_bf16(af, b[n * 2 + kk], acc[n], 0, 0, 0);
        }
    }
#undef STAGE

    // ---- per-wave epilogue ----
    ss += __shfl_xor(ss, 16);
    ss += __shfl_xor(ss, 32);
    float inv = 1.0f / fmaxf(sqrtf(ss), 1e-12f);
    int growbase = rowbase + wave * 16;
    if (lane < 16) invn[growbase + lane] = inv;

    float sc[4];
#pragma unroll
    for (int j = 0; j < 4; ++j) sc[j] = __shfl(inv, lhi * 4 + j) * INV_T;

    float colp[4] = {0.f, 0.f, 0.f, 0.f};
#pragma unroll
    for (int n = 0; n < 4; ++n) {
#pragma unroll
        for (int j = 0; j < 4; ++j) {
            float e = expf(acc[n][j] * sc[j]);
            int row = lhi * 4 + j;  // row & 15
            E[(size_t)(growbase + row) * KC + ((n * 16 + l15) ^ (row << 2))] = e;
            colp[n] += e;
        }
    }
#pragma unroll
    for (int n = 0; n < 4; ++n) {
        colp[n] += __shfl_xor(colp[n], 16);
        colp[n] += __shfl_xor(colp[n], 32);
    }
    if (lane < 16) {
#pragma unroll
        for (int n = 0; n < 4; ++n) bsr[wave][n * 16 + lane] = colp[n];
    }
    __syncthreads();
    if (tid < KC)  // group-atomic fold: 16 blocks/group, distinct addr per lane
        atomicAdd(&PSG0[(size_t)(blockIdx.x >> 4) * KC + tid],
                  bsr[0][tid] + bsr[1][tid] + bsr[2][tid] + bsr[3][tid]);
}

// ---------------- P: sink pass with fused R-chain preamble (two-level PS) ---------
// MODE 2 writes Q TRANSPOSED (QbfT[k][m], bf16): lane=k buffers its 32 consecutive
// m-values in registers, stores as 4x16B = one full 64B line per lane (L2 combines).
template <int MODE>
__global__ __launch_bounds__(256) void k_sink(const float* __restrict__ E,
                                              const float* __restrict__ Rprev,
                                              const float* __restrict__ PSGprev,
                                              const float* __restrict__ invn,
                                              float* __restrict__ c,
                                              float* __restrict__ PSGnext,
                                              float* __restrict__ Rout,
                                              float* __restrict__ Aout,
                                              short* __restrict__ QbfT) {
    __shared__ float tile[SROWS * KC];  // 32 KiB
    __shared__ float sbuf[SROWS];
    __shared__ float Rlds[KC];
    __shared__ float bacc[4][KC];
    int tid = threadIdx.x, lane = tid & 63, wave = tid >> 6;
    int m0 = blockIdx.x * SROWS;

    // issue E staging FIRST (latency hides under the preamble)
#pragma unroll
    for (int i = 0; i < 8; ++i) {
        const float* src = E + (size_t)(m0 + i * 16 + wave * 4 + (lane >> 4)) * KC + (lane & 15) * 4;
        float* dst = tile + (i * 16 + wave * 4) * KC;
        __builtin_amdgcn_global_load_lds((const __attribute__((address_space(1))) void*)src,
                                         (__attribute__((address_space(3))) void*)dst, 16, 0, 0);
    }

    // ---- preamble: PSGprev [64][64] -> R (redundant per block, 16 KB) ----
    {
        int k = tid & 63, g = tid >> 6;
        float s = 0.f;
#pragma unroll
        for (int p = 0; p < PSG_ROWS / 4; ++p) s += PSGprev[(size_t)(g + p * 4) * KC + k];
        bacc[g][k] = s;
        __syncthreads();
        if (tid < KC) {
            float sk = bacc[0][k] + bacc[1][k] + bacc[2][k] + bacc[3][k];
            float r;
            if (MODE == 0) {
                float tot = sk;
                for (int o = 32; o; o >>= 1) tot += __shfl_xor(tot, o);
                float S = fmaxf(tot, 1e-12f);
                r = (1.0f / S) / (fmaxf(sk / S, 1e-12f) * 64.0f);
            } else {
                float rp = Rprev[k];
                r = rp / (fmaxf(rp * sk, 1e-12f) * 64.0f);
            }
            Rlds[k] = r;
            if (MODE != 2) Rout[k] = r;  // all blocks write identical values
        }
    }
    __syncthreads();  // Rlds visible; stage drained (vmcnt 0 at barrier)

    // ---- phase 2: row sums of E_true*R (thread-per-row; R4[j] is wave-uniform) ----
    if (tid < SROWS) {
        const float* rp = tile + tid * KC;
        const f32x4* R4 = (const f32x4*)Rlds;
        int sw = tid & 15;
        f32x4 a = {0.f, 0.f, 0.f, 0.f};
#pragma unroll
        for (int j = 0; j < 16; ++j)
            a += *(const f32x4*)(rp + ((j ^ sw) << 2)) * R4[j];
        sbuf[tid] = a[0] + a[1] + a[2] + a[3];
    }
    __syncthreads();

    // ---- phase 3: lane = k; 32 rows per wave ----
    float Rl = Rlds[lane];
    float wacc = 0.f;
    int rbase = wave * 32;
    short qbuf[32];
#pragma unroll
    for (int r = 0; r < 32; ++r) {
        int rr = rbase + r;
        int m = m0 + rr;
        float e = tile[rr * KC + (lane ^ ((rr & 15) << 2))];  // raw E_true[m][lane]
        float s = sbuf[rr];
        float cold = (MODE == 0) ? 1.0f : c[m];
        float cnew = cold / (fmaxf(cold * s, 1e-12f) * 65536.0f);
        if (MODE == 2) {
            float a = e * Rl * cnew * 65536.0f;
            Aout[(size_t)m * KC + lane] = a;
            qbuf[r] = f2bf(a * invn[m]);
            wacc += a;
        } else {
            if (lane == 0) c[m] = cnew;
            wacc += e * cnew;  // = sum_m E*c directly (no /R needed)
        }
    }
    if (MODE == 2) {
        // pack 32 shorts -> 4x uint4; lane fills QbfT[lane][m0+rbase .. +31] (one 64B line)
        unsigned u[16];
#pragma unroll
        for (int i = 0; i < 16; ++i)
            u[i] = (unsigned)(unsigned short)qbuf[2 * i] | ((unsigned)(unsigned short)qbuf[2 * i + 1] << 16);
        uint4* dst = (uint4*)(QbfT + (size_t)lane * M_TOTAL + m0 + rbase);
#pragma unroll
        for (int i = 0; i < 4; ++i)
            dst[i] = make_uint4(u[4 * i], u[4 * i + 1], u[4 * i + 2], u[4 * i + 3]);
    }
    bacc[wave][lane] = wacc;
    __syncthreads();
    if (tid < KC)  // group-atomic fold: 8 blocks/group
        atomicAdd(&PSGnext[(size_t)(blockIdx.x >> 3) * KC + tid],
                  bacc[0][tid] + bacc[1][tid] + bacc[2][tid] + bacc[3][tid]);
}

// ---------------- K3: weighted centers — Q direct from QbfT (L2-hot), F-only LDS --
// A-fragment: QbfT[kt*16+l15][mb+h*32+lhi*8 ..+7] — coalesced 16-row x 64B global
// loads, 8 MiB total -> L2-resident across all 128 ms blocks. Only F staged in LDS
// ([d][m] XOR-swizzled reg-transpose); LDS 16 KiB; barriers carry half the payload.
__global__ __launch_bounds__(256) void k_weighted(const float* __restrict__ F,
                                                  const short* __restrict__ QbfT,
                                                  float* __restrict__ P) {
    __shared__ short ldsF[DT * MB];  // [d][m] swizzled, 16 KiB
    int tid = threadIdx.x;
    int dt = blockIdx.x;  // 0..5
    int ms = blockIdx.y;  // 0..MSEG-1
    int wave = tid >> 6, lane = tid & 63;
    int l15 = lane & 15, lhi = lane >> 4;

    int m0 = ms * (MB * CH);
    int d0 = dt * DT;

    f32x4 acc[4][2];
#pragma unroll
    for (int kt = 0; kt < 4; ++kt)
#pragma unroll
        for (int ds = 0; ds < 2; ++ds) acc[kt][ds] = (f32x4){0.f, 0.f, 0.f, 0.f};

    int f_dq = (tid & 31) * 4;        // d 0..124 (float4 loads)
    int f_m8 = (tid >> 5) * 8;        // m 0..56

    float4 rf[8];
#define LOADCH(mb_)                                                                       \
    do {                                                                                  \
        _Pragma("unroll") for (int j = 0; j < 8; ++j)                                     \
            rf[j] = *(const float4*)(F + (size_t)((mb_) + f_m8 + j) * DIM + d0 + f_dq);   \
    } while (0)

    LOADCH(m0);
    for (int ch = 0; ch < CH; ++ch) {
        int mb = m0 + ch * MB;
        __syncthreads();  // previous chunk's LDS reads done before overwrite
#pragma unroll
        for (int i = 0; i < 4; ++i) {
            int d = f_dq + i;
            uint4 w;
            w.x = (unsigned)(unsigned short)f2bf(rf[0][i]) | ((unsigned)(unsigned short)f2bf(rf[1][i]) << 16);
            w.y = (unsigned)(unsigned short)f2bf(rf[2][i]) | ((unsigned)(unsigned short)f2bf(rf[3][i]) << 16);
            w.z = (unsigned)(unsigned short)f2bf(rf[4][i]) | ((unsigned)(unsigned short)f2bf(rf[5][i]) << 16);
            w.w = (unsigned)(unsigned short)f2bf(rf[6][i]) | ((unsigned)(unsigned short)f2bf(rf[7][i]) << 16);
            int byte = (d * (MB * 2) + f_m8 * 2) ^ ((d & 7) << 4);
            *(uint4*)((char*)ldsF + byte) = w;
        }
        __syncthreads();
        if (ch + 1 < CH) LOADCH(mb + MB);  // prefetch overlaps MFMA below
#pragma unroll
        for (int h = 0; h < 2; ++h) {
            bf16x8 afr[4];
#pragma unroll
            for (int kt = 0; kt < 4; ++kt)
                afr[kt] = *(const bf16x8*)(QbfT + (size_t)(kt * 16 + l15) * M_TOTAL
                                           + mb + h * 32 + lhi * 8);
#pragma unroll
            for (int ds = 0; ds < 2; ++ds) {
                int d = wave * 32 + ds * 16 + l15;
                int byte = (d * (MB * 2) + (h * 32 + lhi * 8) * 2) ^ ((d & 7) << 4);
                bf16x8 bfr = *(bf16x8*)((char*)ldsF + byte);
#pragma unroll
                for (int kt = 0; kt < 4; ++kt)
                    acc[kt][ds] = __builtin_amdgcn_mfma_f32_16x16x32_bf16(afr[kt], bfr, acc[kt][ds], 0, 0, 0);
            }
        }
    }
#undef LOADCH

    float* Pb = P + (size_t)ms * (KC * DIM) + d0;
#pragma unroll
    for (int kt = 0; kt < 4; ++kt)
#pragma unroll
        for (int ds = 0; ds < 2; ++ds) {
            int d = wave * 32 + ds * 16 + l15;
#pragma unroll
            for (int r4 = 0; r4 < 4; ++r4) {
                int k = kt * 16 + lhi * 4 + r4;
                Pb[(size_t)k * DIM + d] = acc[kt][ds][r4];
            }
        }
}

// ---------------- K4: partial-reduce + mass-reduce + finalize centers -------------
__global__ __launch_bounds__(256) void k_final(const float* __restrict__ P,
                                               const float* __restrict__ PSGM,
                                               const float* __restrict__ cn,
                                               float* __restrict__ outC) {
    int k = blockIdx.x, tid = threadIdx.x;
    __shared__ float red[4];

    float msum = (tid < PSG_ROWS) ? PSGM[(size_t)tid * KC + k] : 0.f;
    for (int o = 32; o; o >>= 1) msum += __shfl_xor(msum, o);
    if ((tid & 63) == 0) red[tid >> 6] = msum;
    __syncthreads();
    float mk = fmaxf(red[0] + red[1] + red[2] + red[3], 1e-6f);
    __syncthreads();

    float w[3];
#pragma unroll
    for (int g = 0; g < 3; ++g) {
        int d = tid + g * 256;
        const float* pp = P + (size_t)k * DIM + d;
        float s0 = 0.f, s1 = 0.f, s2 = 0.f, s3 = 0.f;
        size_t stride = (size_t)KC * DIM;
#pragma unroll 4
        for (int msg = 0; msg < MSEG; msg += 4) {
            s0 += pp[(size_t)msg * stride];
            s1 += pp[(size_t)(msg + 1) * stride];
            s2 += pp[(size_t)(msg + 2) * stride];
            s3 += pp[(size_t)(msg + 3) * stride];
        }
        w[g] = ((s0 + s1) + (s2 + s3)) / mk;
    }

    float ss = w[0] * w[0] + w[1] * w[1] + w[2] * w[2];
    for (int o = 32; o; o >>= 1) ss += __shfl_xor(ss, o);
    if ((tid & 63) == 0) red[tid >> 6] = ss;
    __syncthreads();
    ss = red[0] + red[1] + red[2] + red[3];
    float n1 = fmaxf(sqrtf(ss), 1e-12f);
    __syncthreads();

    float u0 = 0.99f * cn[k * DIM + tid]       + 0.01f * (w[0] / n1);
    float u1 = 0.99f * cn[k * DIM + tid + 256] + 0.01f * (w[1] / n1);
    float u2 = 0.99f * cn[k * DIM + tid + 512] + 0.01f * (w[2] / n1);
    float ss2 = u0 * u0 + u1 * u1 + u2 * u2;
    for (int o = 32; o; o >>= 1) ss2 += __shfl_xor(ss2, o);
    if ((tid & 63) == 0) red[tid >> 6] = ss2;
    __syncthreads();
    ss2 = red[0] + red[1] + red[2] + red[3];
    float n2 = fmaxf(sqrtf(ss2), 1e-12f);

    outC[k * DIM + tid]       = u0 / n2;
    outC[k * DIM + tid + 256] = u1 / n2;
    outC[k * DIM + tid + 512] = u2 / n2;
}

extern "C" void kernel_launch(void* const* d_in, const int* in_sizes, int n_in,
                              void* d_out, int out_size, void* d_ws, size_t ws_size,
                              hipStream_t stream) {
    const float* F = (const float*)d_in[0];        // [65536][768]
    const float* centers = (const float*)d_in[1];  // [64][768]
    float* out = (float*)d_out;
    float* A = out;                                 // assignments [65536][64]
    float* outC = out + (size_t)M_TOTAL * KC;       // updated centers [64][768]

    float* w = (float*)d_ws;                        // ws = 768 MiB
    float* cn   = w;                                // 49152
    short* cnbf = (short*)(w + 49152);              // 24576 float slots
    float* R0   = w + 73728;                        // 64
    float* R1   = w + 73792;                        // 64
    float* invn = w + 74048;                        // 65536
    float* cbuf = w + 139584;                       // 65536
    float* E    = w + 205120;                       // 4194304 (pre-swizzled layout)
    short* QbfT = (short*)(w + 4399424);            // [64][65536] bf16 = 8 MiB
    float* PSG  = w + 6496576;                      // 4 x [64][64] = 16384 floats
    float* PSG0 = PSG;
    float* PSG1 = PSG + 4096;
    float* PSG2 = PSG + 8192;
    float* PSGM = PSG + 12288;
    float* partial = w + 6520000;                   // MSEG*64*768 = 6291456 (24 MiB)

    k_centers<<<KC, 256, 0, stream>>>(centers, cn, cnbf, PSG);
    k_logits<<<LOGITS_BLOCKS, 256, 0, stream>>>(F, cnbf, E, invn, PSG0);
    k_sink<0><<<SINK_BLOCKS, 256, 0, stream>>>(E, nullptr, PSG0, invn, cbuf, PSG1, R0, A, QbfT);
    k_sink<1><<<SINK_BLOCKS, 256, 0, stream>>>(E, R0, PSG1, invn, cbuf, PSG2, R1, A, QbfT);
    k_sink<2><<<SINK_BLOCKS, 256, 0, stream>>>(E, R1, PSG2, invn, cbuf, PSGM, nullptr, A, QbfT);

    dim3 wgrid(DIM / DT, MSEG);
    k_weighted<<<wgrid, 256, 0, stream>>>(F, QbfT, partial);
    k_final<<<KC, 256, 0, stream>>>(partial, PSGM, cn, outC);
}

// Round 14
// 161.408 us; speedup vs baseline: 1.0048x; 1.0048x over previous
//
#include <hip/hip_runtime.h>
#include <hip/hip_bf16.h>

#define M_TOTAL 65536
#define DIM 768
#define KC 64
#define INV_T 10.0f

// k_weighted tiling
#define DT 128    // d-cols per block
#define MB 64     // m per LDS chunk
#define CH 8      // chunks per block (m-range 512)
#define MSEG 128  // m-segments (partials)

#define LOGITS_BLOCKS (M_TOTAL / 64)   // 1024 (64 rows per block)
#define SROWS 128
#define SINK_BLOCKS (M_TOTAL / SROWS)  // 512
#define PSG_ROWS 64                    // two-level PS: 64 group rows of 64 floats

typedef __attribute__((ext_vector_type(4))) float f32x4;
typedef __attribute__((ext_vector_type(8))) short bf16x8;
typedef __attribute__((ext_vector_type(4))) unsigned short u16x4;

__device__ __forceinline__ short f2bf(float f) {
    __hip_bfloat16 h = __float2bfloat16(f);
    union { __hip_bfloat16 h; short s; } u; u.h = h;
    return u.s;
}

// ---------------- K0: normalize centers -> cn + cnbf; zero PSG --------------------
__global__ __launch_bounds__(256) void k_centers(const float* __restrict__ centers,
                                                 float* __restrict__ cn,
                                                 short* __restrict__ cnbf,
                                                 float* __restrict__ psg) {
    int k = blockIdx.x, tid = threadIdx.x;
    psg[k * 256 + tid] = 0.f;  // 64*256 = 16384 = all four PSG arrays
    float ss = 0.f;
    for (int i = tid; i < DIM; i += 256) { float v = centers[k * DIM + i]; ss += v * v; }
    __shared__ float red[4];
    for (int o = 32; o; o >>= 1) ss += __shfl_xor(ss, o);
    if ((tid & 63) == 0) red[tid >> 6] = ss;
    __syncthreads();
    ss = red[0] + red[1] + red[2] + red[3];
    float inv = 1.0f / fmaxf(sqrtf(ss), 1e-12f);
    for (int i = tid; i < DIM; i += 256) {
        float v = centers[k * DIM + i] * inv;
        cn[k * DIM + i] = v;
        cnbf[k * DIM + i] = f2bf(v);
    }
}

// ---------------- K1: logits GEMM — wave-autonomous, barrier-free pipeline --------
// (unchanged from R12)
__global__ __launch_bounds__(256) void k_logits(const float* __restrict__ F,
                                                const short* __restrict__ cnbf,
                                                float* __restrict__ E,
                                                float* __restrict__ invn,
                                                float* __restrict__ PSG0) {
    __shared__ float fbuf[3][4][1024];  // [buf][wave][16 rows x 64 cols], 48 KiB
    __shared__ float bsr[4][KC];
    int tid = threadIdx.x;
    int wave = tid >> 6, lane = tid & 63;
    int l15 = lane & 15, lhi = lane >> 4;
    int rowbase = blockIdx.x * 64;

    int srow_l = lane >> 4;          // row within 4-row group
    int c4 = lane & 15;              // col granule (16B)

#define STAGE(t_, b_)                                                                     \
    do {                                                                                  \
        _Pragma("unroll") for (int i_ = 0; i_ < 4; ++i_) {                                \
            int r_ = i_ * 4 + srow_l;  /* local row 0..15 */                              \
            const float* src_ = F + (size_t)(rowbase + wave * 16 + r_) * DIM + (t_) * 64  \
                                + (((c4 ^ (r_ & 7)) << 2));                               \
            float* dst_ = &fbuf[b_][wave][i_ * 256];                                      \
            __builtin_amdgcn_global_load_lds(                                             \
                (const __attribute__((address_space(1))) void*)src_,                      \
                (__attribute__((address_space(3))) void*)dst_, 16, 0, 0);                 \
        }                                                                                 \
    } while (0)

    STAGE(0, 0);
    STAGE(1, 1);

    f32x4 acc[4];
#pragma unroll
    for (int n = 0; n < 4; ++n) acc[n] = (f32x4){0.f, 0.f, 0.f, 0.f};
    float ss = 0.f;

    const short* Bb = cnbf + (size_t)l15 * DIM + lhi * 8;
    int swz = (l15 & 7) << 2;

#pragma unroll
    for (int t = 0; t < 12; ++t) {
        bf16x8 b[8];
#pragma unroll
        for (int n = 0; n < 4; ++n) {
            b[n * 2]     = *(const bf16x8*)(Bb + (size_t)n * 16 * DIM + t * 64);
            b[n * 2 + 1] = *(const bf16x8*)(Bb + (size_t)n * 16 * DIM + t * 64 + 32);
        }
        if (t + 2 < 12) {
            STAGE(t + 2, (t + 2) % 3);
            asm volatile("s_waitcnt vmcnt(4)" ::: "memory");  // S(t)+B(t) done; S(t+2) in flight
        } else {
            asm volatile("s_waitcnt vmcnt(0)" ::: "memory");
        }
        __builtin_amdgcn_sched_barrier(0);
        const float* cb = &fbuf[t % 3][wave][l15 * 64];
#pragma unroll
        for (int kk = 0; kk < 2; ++kk) {
            int c0s = (kk * 32 + lhi * 8) ^ swz;
            f32x4 fa = *(const f32x4*)(cb + c0s);
            f32x4 fb2 = *(const f32x4*)(cb + (c0s ^ 4));
            ss += fa[0] * fa[0] + fa[1] * fa[1] + fa[2] * fa[2] + fa[3] * fa[3]
                + fb2[0] * fb2[0] + fb2[1] * fb2[1] + fb2[2] * fb2[2] + fb2[3] * fb2[3];
            bf16x8 af;
            af[0] = f2bf(fa[0]); af[1] = f2bf(fa[1]); af[2] = f2bf(fa[2]); af[3] = f2bf(fa[3]);
            af[4] = f2bf(fb2[0]); af[5] = f2bf(fb2[1]); af[6] = f2bf(fb2[2]); af[7] = f2bf(fb2[3]);
#pragma unroll
            for (int n = 0; n < 4; ++n)
                acc[n] = __builtin_amdgcn_mfma_f32_16x16x32_bf16(af, b[n * 2 + kk], acc[n], 0, 0, 0);
        }
    }
#undef STAGE

    // ---- per-wave epilogue ----
    ss += __shfl_xor(ss, 16);
    ss += __shfl_xor(ss, 32);
    float inv = 1.0f / fmaxf(sqrtf(ss), 1e-12f);
    int growbase = rowbase + wave * 16;
    if (lane < 16) invn[growbase + lane] = inv;

    float sc[4];
#pragma unroll
    for (int j = 0; j < 4; ++j) sc[j] = __shfl(inv, lhi * 4 + j) * INV_T;

    float colp[4] = {0.f, 0.f, 0.f, 0.f};
#pragma unroll
    for (int n = 0; n < 4; ++n) {
#pragma unroll
        for (int j = 0; j < 4; ++j) {
            float e = expf(acc[n][j] * sc[j]);
            int row = lhi * 4 + j;  // row & 15
            E[(size_t)(growbase + row) * KC + ((n * 16 + l15) ^ (row << 2))] = e;
            colp[n] += e;
        }
    }
#pragma unroll
    for (int n = 0; n < 4; ++n) {
        colp[n] += __shfl_xor(colp[n], 16);
        colp[n] += __shfl_xor(colp[n], 32);
    }
    if (lane < 16) {
#pragma unroll
        for (int n = 0; n < 4; ++n) bsr[wave][n * 16 + lane] = colp[n];
    }
    __syncthreads();
    if (tid < KC)  // group-atomic fold: 16 blocks/group, distinct addr per lane
        atomicAdd(&PSG0[(size_t)(blockIdx.x >> 4) * KC + tid],
                  bsr[0][tid] + bsr[1][tid] + bsr[2][tid] + bsr[3][tid]);
}

// ---------------- P: sink pass with fused R-chain preamble (two-level PS) ---------
// MODE 2: qbuf routed through LDS (stride-130 rows, all accesses <=2-way bank) and
// written to QbfT[k][m] with 16-lanes-per-row mapping -> 256B-contiguous stores.
template <int MODE>
__global__ __launch_bounds__(256) void k_sink(const float* __restrict__ E,
                                              const float* __restrict__ Rprev,
                                              const float* __restrict__ PSGprev,
                                              const float* __restrict__ invn,
                                              float* __restrict__ c,
                                              float* __restrict__ PSGnext,
                                              float* __restrict__ Rout,
                                              float* __restrict__ Aout,
                                              short* __restrict__ QbfT) {
    __shared__ float tile[SROWS * KC];  // 32 KiB (re-used as qT in MODE 2 epilogue)
    __shared__ float sbuf[SROWS];
    __shared__ float Rlds[KC];
    __shared__ float bacc[4][KC];
    int tid = threadIdx.x, lane = tid & 63, wave = tid >> 6;
    int m0 = blockIdx.x * SROWS;

    // issue E staging FIRST (latency hides under the preamble)
#pragma unroll
    for (int i = 0; i < 8; ++i) {
        const float* src = E + (size_t)(m0 + i * 16 + wave * 4 + (lane >> 4)) * KC + (lane & 15) * 4;
        float* dst = tile + (i * 16 + wave * 4) * KC;
        __builtin_amdgcn_global_load_lds((const __attribute__((address_space(1))) void*)src,
                                         (__attribute__((address_space(3))) void*)dst, 16, 0, 0);
    }

    // ---- preamble: PSGprev [64][64] -> R (redundant per block, 16 KB) ----
    {
        int k = tid & 63, g = tid >> 6;
        float s = 0.f;
#pragma unroll
        for (int p = 0; p < PSG_ROWS / 4; ++p) s += PSGprev[(size_t)(g + p * 4) * KC + k];
        bacc[g][k] = s;
        __syncthreads();
        if (tid < KC) {
            float sk = bacc[0][k] + bacc[1][k] + bacc[2][k] + bacc[3][k];
            float r;
            if (MODE == 0) {
                float tot = sk;
                for (int o = 32; o; o >>= 1) tot += __shfl_xor(tot, o);
                float S = fmaxf(tot, 1e-12f);
                r = (1.0f / S) / (fmaxf(sk / S, 1e-12f) * 64.0f);
            } else {
                float rp = Rprev[k];
                r = rp / (fmaxf(rp * sk, 1e-12f) * 64.0f);
            }
            Rlds[k] = r;
            if (MODE != 2) Rout[k] = r;  // all blocks write identical values
        }
    }
    __syncthreads();  // Rlds visible; stage drained (vmcnt 0 at barrier)

    // ---- phase 2: row sums of E_true*R (thread-per-row; R4[j] is wave-uniform) ----
    if (tid < SROWS) {
        const float* rp = tile + tid * KC;
        const f32x4* R4 = (const f32x4*)Rlds;
        int sw = tid & 15;
        f32x4 a = {0.f, 0.f, 0.f, 0.f};
#pragma unroll
        for (int j = 0; j < 16; ++j)
            a += *(const f32x4*)(rp + ((j ^ sw) << 2)) * R4[j];
        sbuf[tid] = a[0] + a[1] + a[2] + a[3];
    }
    __syncthreads();

    // ---- phase 3: lane = k; 32 rows per wave ----
    float Rl = Rlds[lane];
    float wacc = 0.f;
    int rbase = wave * 32;
    short qbuf[32];
#pragma unroll
    for (int r = 0; r < 32; ++r) {
        int rr = rbase + r;
        int m = m0 + rr;
        float e = tile[rr * KC + (lane ^ ((rr & 15) << 2))];  // raw E_true[m][lane]
        float s = sbuf[rr];
        float cold = (MODE == 0) ? 1.0f : c[m];
        float cnew = cold / (fmaxf(cold * s, 1e-12f) * 65536.0f);
        if (MODE == 2) {
            float a = e * Rl * cnew * 65536.0f;
            Aout[(size_t)m * KC + lane] = a;
            qbuf[r] = f2bf(a * invn[m]);
            wacc += a;
        } else {
            if (lane == 0) c[m] = cnew;
            wacc += e * cnew;  // = sum_m E*c directly (no /R needed)
        }
    }
    bacc[wave][lane] = wacc;
    __syncthreads();  // bacc ready; ALL phase-3 tile reads done (tile reusable)

    if (MODE == 2) {
        // LDS transpose staging: qT[k][m_local], row stride 130 shorts (bank-free)
        short* qT = (short*)tile;  // 64*130*2 = 16640 B <= 32 KiB
#pragma unroll
        for (int i = 0; i < 4; ++i) {
            unsigned a0 = (unsigned)(unsigned short)qbuf[8 * i]     | ((unsigned)(unsigned short)qbuf[8 * i + 1] << 16);
            unsigned a1 = (unsigned)(unsigned short)qbuf[8 * i + 2] | ((unsigned)(unsigned short)qbuf[8 * i + 3] << 16);
            unsigned a2 = (unsigned)(unsigned short)qbuf[8 * i + 4] | ((unsigned)(unsigned short)qbuf[8 * i + 5] << 16);
            unsigned a3 = (unsigned)(unsigned short)qbuf[8 * i + 6] | ((unsigned)(unsigned short)qbuf[8 * i + 7] << 16);
            *(uint4*)(qT + lane * 130 + rbase + i * 8) = make_uint4(a0, a1, a2, a3);
        }
        __syncthreads();
        // coalesced write-out: 16 lanes per k-row, 256B contiguous per row per instr
        int k4 = tid >> 4;    // 0..15
        int c16 = tid & 15;   // 16B chunk within 256B row
#pragma unroll
        for (int pass = 0; pass < 4; ++pass) {
            int k = pass * 16 + k4;
            *(uint4*)(QbfT + (size_t)k * M_TOTAL + m0 + c16 * 8) =
                *(const uint4*)(qT + k * 130 + c16 * 8);
        }
    }

    if (tid < KC)  // group-atomic fold: 8 blocks/group
        atomicAdd(&PSGnext[(size_t)(blockIdx.x >> 3) * KC + tid],
                  bacc[0][tid] + bacc[1][tid] + bacc[2][tid] + bacc[3][tid]);
}

// ---------------- K3: weighted centers — QbfT direct + register double-buffer -----
// Q-fragments (qA/qB) and F rows (rf) prefetched one chunk ahead; parity made
// static via 2x-unrolled body macro (rule #20). LDS = F only, 16 KiB.
__global__ __launch_bounds__(256) void k_weighted(const float* __restrict__ F,
                                                  const short* __restrict__ QbfT,
                                                  float* __restrict__ P) {
    __shared__ short ldsF[DT * MB];  // [d][m] swizzled, 16 KiB
    int tid = threadIdx.x;
    int dt = blockIdx.x;  // 0..5
    int ms = blockIdx.y;  // 0..MSEG-1
    int wave = tid >> 6, lane = tid & 63;
    int l15 = lane & 15, lhi = lane >> 4;

    int m0 = ms * (MB * CH);
    int d0 = dt * DT;

    f32x4 acc[4][2];
#pragma unroll
    for (int kt = 0; kt < 4; ++kt)
#pragma unroll
        for (int ds = 0; ds < 2; ++ds) acc[kt][ds] = (f32x4){0.f, 0.f, 0.f, 0.f};

    int f_dq = (tid & 31) * 4;        // d 0..124 (float4 loads)
    int f_m8 = (tid >> 5) * 8;        // m 0..56

    float4 rf[8];
    bf16x8 qA[8], qB[8];

#define LOADCH(mb_)                                                                       \
    do {                                                                                  \
        _Pragma("unroll") for (int j = 0; j < 8; ++j)                                     \
            rf[j] = *(const float4*)(F + (size_t)((mb_) + f_m8 + j) * DIM + d0 + f_dq);   \
    } while (0)

#define QLOAD(mb_, ARR)                                                                   \
    do {                                                                                  \
        _Pragma("unroll") for (int h_ = 0; h_ < 2; ++h_)                                  \
            _Pragma("unroll") for (int kt_ = 0; kt_ < 4; ++kt_)                           \
                ARR[h_ * 4 + kt_] = *(const bf16x8*)(QbfT                                 \
                    + (size_t)(kt_ * 16 + l15) * M_TOTAL + (mb_) + h_ * 32 + lhi * 8);    \
    } while (0)

#define BODY(ch_, QC, QN)                                                                 \
    {                                                                                     \
        int mb_ = m0 + (ch_) * MB;                                                        \
        __syncthreads();                                                                  \
        _Pragma("unroll") for (int i = 0; i < 4; ++i) {                                   \
            int d = f_dq + i;                                                             \
            uint4 w;                                                                      \
            w.x = (unsigned)(unsigned short)f2bf(rf[0][i]) | ((unsigned)(unsigned short)f2bf(rf[1][i]) << 16); \
            w.y = (unsigned)(unsigned short)f2bf(rf[2][i]) | ((unsigned)(unsigned short)f2bf(rf[3][i]) << 16); \
            w.z = (unsigned)(unsigned short)f2bf(rf[4][i]) | ((unsigned)(unsigned short)f2bf(rf[5][i]) << 16); \
            w.w = (unsigned)(unsigned short)f2bf(rf[6][i]) | ((unsigned)(unsigned short)f2bf(rf[7][i]) << 16); \
            int byte = (d * (MB * 2) + f_m8 * 2) ^ ((d & 7) << 4);                        \
            *(uint4*)((char*)ldsF + byte) = w;                                            \
        }                                                                                 \
        __syncthreads();                                                                  \
        if ((ch_) + 1 < CH) { LOADCH(mb_ + MB); QLOAD(mb_ + MB, QN); }                    \
        _Pragma("unroll") for (int h = 0; h < 2; ++h) {                                   \
            _Pragma("unroll") for (int ds = 0; ds < 2; ++ds) {                            \
                int d = wave * 32 + ds * 16 + l15;                                        \
                int byte = (d * (MB * 2) + (h * 32 + lhi * 8) * 2) ^ ((d & 7) << 4);      \
                bf16x8 bfr = *(bf16x8*)((char*)ldsF + byte);                              \
                _Pragma("unroll") for (int kt = 0; kt < 4; ++kt)                          \
                    acc[kt][ds] = __builtin_amdgcn_mfma_f32_16x16x32_bf16(                \
                        QC[h * 4 + kt], bfr, acc[kt][ds], 0, 0, 0);                       \
            }                                                                             \
        }                                                                                 \
    }

    LOADCH(m0);
    QLOAD(m0, qA);
    for (int cc = 0; cc < CH; cc += 2) {
        BODY(cc, qA, qB);
        BODY(cc + 1, qB, qA);
    }
#undef BODY
#undef QLOAD
#undef LOADCH

    float* Pb = P + (size_t)ms * (KC * DIM) + d0;
#pragma unroll
    for (int kt = 0; kt < 4; ++kt)
#pragma unroll
        for (int ds = 0; ds < 2; ++ds) {
            int d = wave * 32 + ds * 16 + l15;
#pragma unroll
            for (int r4 = 0; r4 < 4; ++r4) {
                int k = kt * 16 + lhi * 4 + r4;
                Pb[(size_t)k * DIM + d] = acc[kt][ds][r4];
            }
        }
}

// ---------------- K4: partial-reduce + mass-reduce + finalize centers -------------
__global__ __launch_bounds__(256) void k_final(const float* __restrict__ P,
                                               const float* __restrict__ PSGM,
                                               const float* __restrict__ cn,
                                               float* __restrict__ outC) {
    int k = blockIdx.x, tid = threadIdx.x;
    __shared__ float red[4];

    float msum = (tid < PSG_ROWS) ? PSGM[(size_t)tid * KC + k] : 0.f;
    for (int o = 32; o; o >>= 1) msum += __shfl_xor(msum, o);
    if ((tid & 63) == 0) red[tid >> 6] = msum;
    __syncthreads();
    float mk = fmaxf(red[0] + red[1] + red[2] + red[3], 1e-6f);
    __syncthreads();

    float w[3];
#pragma unroll
    for (int g = 0; g < 3; ++g) {
        int d = tid + g * 256;
        const float* pp = P + (size_t)k * DIM + d;
        float s0 = 0.f, s1 = 0.f, s2 = 0.f, s3 = 0.f;
        size_t stride = (size_t)KC * DIM;
#pragma unroll 4
        for (int msg = 0; msg < MSEG; msg += 4) {
            s0 += pp[(size_t)msg * stride];
            s1 += pp[(size_t)(msg + 1) * stride];
            s2 += pp[(size_t)(msg + 2) * stride];
            s3 += pp[(size_t)(msg + 3) * stride];
        }
        w[g] = ((s0 + s1) + (s2 + s3)) / mk;
    }

    float ss = w[0] * w[0] + w[1] * w[1] + w[2] * w[2];
    for (int o = 32; o; o >>= 1) ss += __shfl_xor(ss, o);
    if ((tid & 63) == 0) red[tid >> 6] = ss;
    __syncthreads();
    ss = red[0] + red[1] + red[2] + red[3];
    float n1 = fmaxf(sqrtf(ss), 1e-12f);
    __syncthreads();

    float u0 = 0.99f * cn[k * DIM + tid]       + 0.01f * (w[0] / n1);
    float u1 = 0.99f * cn[k * DIM + tid + 256] + 0.01f * (w[1] / n1);
    float u2 = 0.99f * cn[k * DIM + tid + 512] + 0.01f * (w[2] / n1);
    float ss2 = u0 * u0 + u1 * u1 + u2 * u2;
    for (int o = 32; o; o >>= 1) ss2 += __shfl_xor(ss2, o);
    if ((tid & 63) == 0) red[tid >> 6] = ss2;
    __syncthreads();
    ss2 = red[0] + red[1] + red[2] + red[3];
    float n2 = fmaxf(sqrtf(ss2), 1e-12f);

    outC[k * DIM + tid]       = u0 / n2;
    outC[k * DIM + tid + 256] = u1 / n2;
    outC[k * DIM + tid + 512] = u2 / n2;
}

extern "C" void kernel_launch(void* const* d_in, const int* in_sizes, int n_in,
                              void* d_out, int out_size, void* d_ws, size_t ws_size,
                              hipStream_t stream) {
    const float* F = (const float*)d_in[0];        // [65536][768]
    const float* centers = (const float*)d_in[1];  // [64][768]
    float* out = (float*)d_out;
    float* A = out;                                 // assignments [65536][64]
    float* outC = out + (size_t)M_TOTAL * KC;       // updated centers [64][768]

    float* w = (float*)d_ws;                        // ws = 768 MiB
    float* cn   = w;                                // 49152
    short* cnbf = (short*)(w + 49152);              // 24576 float slots
    float* R0   = w + 73728;                        // 64
    float* R1   = w + 73792;                        // 64
    float* invn = w + 74048;                        // 65536
    float* cbuf = w + 139584;                       // 65536
    float* E    = w + 205120;                       // 4194304 (pre-swizzled layout)
    short* QbfT = (short*)(w + 4399424);            // [64][65536] bf16 = 8 MiB
    float* PSG  = w + 6496576;                      // 4 x [64][64] = 16384 floats
    float* PSG0 = PSG;
    float* PSG1 = PSG + 4096;
    float* PSG2 = PSG + 8192;
    float* PSGM = PSG + 12288;
    float* partial = w + 6520000;                   // MSEG*64*768 = 6291456 (24 MiB)

    k_centers<<<KC, 256, 0, stream>>>(centers, cn, cnbf, PSG);
    k_logits<<<LOGITS_BLOCKS, 256, 0, stream>>>(F, cnbf, E, invn, PSG0);
    k_sink<0><<<SINK_BLOCKS, 256, 0, stream>>>(E, nullptr, PSG0, invn, cbuf, PSG1, R0, A, QbfT);
    k_sink<1><<<SINK_BLOCKS, 256, 0, stream>>>(E, R0, PSG1, invn, cbuf, PSG2, R1, A, QbfT);
    k_sink<2><<<SINK_BLOCKS, 256, 0, stream>>>(E, R1, PSG2, invn, cbuf, PSGM, nullptr, A, QbfT);

    dim3 wgrid(DIM / DT, MSEG);
    k_weighted<<<wgrid, 256, 0, stream>>>(F, QbfT, partial);
    k_final<<<KC, 256, 0, stream>>>(partial, PSGM, cn, outC);
}

// Round 15
// 156.700 us; speedup vs baseline: 1.0350x; 1.0300x over previous
//
#include <hip/hip_runtime.h>
#include <hip/hip_bf16.h>

#define M_TOTAL 65536
#define DIM 768
#define KC 64
#define INV_T 10.0f

// k_weighted tiling
#define DT 128    // d-cols per block
#define MB 64     // m per LDS chunk
#define CH 8      // chunks per block (m-range 512)
#define MSEG 128  // m-segments (partials)

#define LOGITS_BLOCKS (M_TOTAL / 64)   // 1024 (64 rows per block)
#define SROWS 128
#define SINK_BLOCKS (M_TOTAL / SROWS)  // 512
#define PSG_ROWS 64                    // two-level PS: 64 group rows of 64 floats

typedef __attribute__((ext_vector_type(4))) float f32x4;
typedef __attribute__((ext_vector_type(8))) short bf16x8;
typedef __attribute__((ext_vector_type(4))) unsigned short u16x4;

__device__ __forceinline__ short f2bf(float f) {
    __hip_bfloat16 h = __float2bfloat16(f);
    union { __hip_bfloat16 h; short s; } u; u.h = h;
    return u.s;
}

// ---------------- K0: normalize centers -> cn + cnbf; zero PSG --------------------
__global__ __launch_bounds__(256) void k_centers(const float* __restrict__ centers,
                                                 float* __restrict__ cn,
                                                 short* __restrict__ cnbf,
                                                 float* __restrict__ psg) {
    int k = blockIdx.x, tid = threadIdx.x;
    psg[k * 256 + tid] = 0.f;  // 64*256 = 16384 = all four PSG arrays
    float ss = 0.f;
    for (int i = tid; i < DIM; i += 256) { float v = centers[k * DIM + i]; ss += v * v; }
    __shared__ float red[4];
    for (int o = 32; o; o >>= 1) ss += __shfl_xor(ss, o);
    if ((tid & 63) == 0) red[tid >> 6] = ss;
    __syncthreads();
    ss = red[0] + red[1] + red[2] + red[3];
    float inv = 1.0f / fmaxf(sqrtf(ss), 1e-12f);
    for (int i = tid; i < DIM; i += 256) {
        float v = centers[k * DIM + i] * inv;
        cn[k * DIM + i] = v;
        cnbf[k * DIM + i] = f2bf(v);
    }
}

// ---------------- K1: logits GEMM — wave-autonomous, barrier-free pipeline --------
__global__ __launch_bounds__(256) void k_logits(const float* __restrict__ F,
                                                const short* __restrict__ cnbf,
                                                float* __restrict__ E,
                                                float* __restrict__ invn,
                                                float* __restrict__ PSG0) {
    __shared__ float fbuf[3][4][1024];  // [buf][wave][16 rows x 64 cols], 48 KiB
    __shared__ float bsr[4][KC];
    int tid = threadIdx.x;
    int wave = tid >> 6, lane = tid & 63;
    int l15 = lane & 15, lhi = lane >> 4;
    int rowbase = blockIdx.x * 64;

    int srow_l = lane >> 4;          // row within 4-row group
    int c4 = lane & 15;              // col granule (16B)

#define STAGE(t_, b_)                                                                     \
    do {                                                                                  \
        _Pragma("unroll") for (int i_ = 0; i_ < 4; ++i_) {                                \
            int r_ = i_ * 4 + srow_l;  /* local row 0..15 */                              \
            const float* src_ = F + (size_t)(rowbase + wave * 16 + r_) * DIM + (t_) * 64  \
                                + (((c4 ^ (r_ & 7)) << 2));                               \
            float* dst_ = &fbuf[b_][wave][i_ * 256];                                      \
            __builtin_amdgcn_global_load_lds(                                             \
                (const __attribute__((address_space(1))) void*)src_,                      \
                (__attribute__((address_space(3))) void*)dst_, 16, 0, 0);                 \
        }                                                                                 \
    } while (0)

    STAGE(0, 0);
    STAGE(1, 1);

    f32x4 acc[4];
#pragma unroll
    for (int n = 0; n < 4; ++n) acc[n] = (f32x4){0.f, 0.f, 0.f, 0.f};
    float ss = 0.f;

    const short* Bb = cnbf + (size_t)l15 * DIM + lhi * 8;
    int swz = (l15 & 7) << 2;

#pragma unroll
    for (int t = 0; t < 12; ++t) {
        bf16x8 b[8];
#pragma unroll
        for (int n = 0; n < 4; ++n) {
            b[n * 2]     = *(const bf16x8*)(Bb + (size_t)n * 16 * DIM + t * 64);
            b[n * 2 + 1] = *(const bf16x8*)(Bb + (size_t)n * 16 * DIM + t * 64 + 32);
        }
        if (t + 2 < 12) {
            STAGE(t + 2, (t + 2) % 3);
            asm volatile("s_waitcnt vmcnt(4)" ::: "memory");  // S(t)+B(t) done; S(t+2) in flight
        } else {
            asm volatile("s_waitcnt vmcnt(0)" ::: "memory");
        }
        __builtin_amdgcn_sched_barrier(0);
        const float* cb = &fbuf[t % 3][wave][l15 * 64];
#pragma unroll
        for (int kk = 0; kk < 2; ++kk) {
            int c0s = (kk * 32 + lhi * 8) ^ swz;
            f32x4 fa = *(const f32x4*)(cb + c0s);
            f32x4 fb2 = *(const f32x4*)(cb + (c0s ^ 4));
            ss += fa[0] * fa[0] + fa[1] * fa[1] + fa[2] * fa[2] + fa[3] * fa[3]
                + fb2[0] * fb2[0] + fb2[1] * fb2[1] + fb2[2] * fb2[2] + fb2[3] * fb2[3];
            bf16x8 af;
            af[0] = f2bf(fa[0]); af[1] = f2bf(fa[1]); af[2] = f2bf(fa[2]); af[3] = f2bf(fa[3]);
            af[4] = f2bf(fb2[0]); af[5] = f2bf(fb2[1]); af[6] = f2bf(fb2[2]); af[7] = f2bf(fb2[3]);
#pragma unroll
            for (int n = 0; n < 4; ++n)
                acc[n] = __builtin_amdgcn_mfma_f32_16x16x32_bf16(af, b[n * 2 + kk], acc[n], 0, 0, 0);
        }
    }
#undef STAGE

    // ---- per-wave epilogue ----
    ss += __shfl_xor(ss, 16);
    ss += __shfl_xor(ss, 32);
    float inv = 1.0f / fmaxf(sqrtf(ss), 1e-12f);
    int growbase = rowbase + wave * 16;
    if (lane < 16) invn[growbase + lane] = inv;

    float sc[4];
#pragma unroll
    for (int j = 0; j < 4; ++j) sc[j] = __shfl(inv, lhi * 4 + j) * INV_T;

    float colp[4] = {0.f, 0.f, 0.f, 0.f};
#pragma unroll
    for (int n = 0; n < 4; ++n) {
#pragma unroll
        for (int j = 0; j < 4; ++j) {
            float e = expf(acc[n][j] * sc[j]);
            int row = lhi * 4 + j;  // row & 15
            E[(size_t)(growbase + row) * KC + ((n * 16 + l15) ^ (row << 2))] = e;
            colp[n] += e;
        }
    }
#pragma unroll
    for (int n = 0; n < 4; ++n) {
        colp[n] += __shfl_xor(colp[n], 16);
        colp[n] += __shfl_xor(colp[n], 32);
    }
    if (lane < 16) {
#pragma unroll
        for (int n = 0; n < 4; ++n) bsr[wave][n * 16 + lane] = colp[n];
    }
    __syncthreads();
    if (tid < KC)  // group-atomic fold: 16 blocks/group, distinct addr per lane
        atomicAdd(&PSG0[(size_t)(blockIdx.x >> 4) * KC + tid],
                  bsr[0][tid] + bsr[1][tid] + bsr[2][tid] + bsr[3][tid]);
}

// ---------------- P: sink pass with fused R-chain preamble (two-level PS) ---------
template <int MODE>
__global__ __launch_bounds__(256) void k_sink(const float* __restrict__ E,
                                              const float* __restrict__ Rprev,
                                              const float* __restrict__ PSGprev,
                                              const float* __restrict__ invn,
                                              float* __restrict__ c,
                                              float* __restrict__ PSGnext,
                                              float* __restrict__ Rout,
                                              float* __restrict__ Aout,
                                              short* __restrict__ Qbf) {
    __shared__ float tile[SROWS * KC];  // 32 KiB
    __shared__ float sbuf[SROWS];
    __shared__ float Rlds[KC];
    __shared__ float bacc[4][KC];
    int tid = threadIdx.x, lane = tid & 63, wave = tid >> 6;
    int m0 = blockIdx.x * SROWS;

    // issue E staging FIRST (latency hides under the preamble)
#pragma unroll
    for (int i = 0; i < 8; ++i) {
        const float* src = E + (size_t)(m0 + i * 16 + wave * 4 + (lane >> 4)) * KC + (lane & 15) * 4;
        float* dst = tile + (i * 16 + wave * 4) * KC;
        __builtin_amdgcn_global_load_lds((const __attribute__((address_space(1))) void*)src,
                                         (__attribute__((address_space(3))) void*)dst, 16, 0, 0);
    }

    // ---- preamble: PSGprev [64][64] -> R (redundant per block, 16 KB) ----
    {
        int k = tid & 63, g = tid >> 6;
        float s = 0.f;
#pragma unroll
        for (int p = 0; p < PSG_ROWS / 4; ++p) s += PSGprev[(size_t)(g + p * 4) * KC + k];
        bacc[g][k] = s;
        __syncthreads();
        if (tid < KC) {
            float sk = bacc[0][k] + bacc[1][k] + bacc[2][k] + bacc[3][k];
            float r;
            if (MODE == 0) {
                float tot = sk;
                for (int o = 32; o; o >>= 1) tot += __shfl_xor(tot, o);
                float S = fmaxf(tot, 1e-12f);
                r = (1.0f / S) / (fmaxf(sk / S, 1e-12f) * 64.0f);
            } else {
                float rp = Rprev[k];
                r = rp / (fmaxf(rp * sk, 1e-12f) * 64.0f);
            }
            Rlds[k] = r;
            if (MODE != 2) Rout[k] = r;  // all blocks write identical values
        }
    }
    __syncthreads();  // Rlds visible; stage drained (vmcnt 0 at barrier)

    // ---- phase 2: row sums of E_true*R (thread-per-row; R4[j] is wave-uniform) ----
    if (tid < SROWS) {
        const float* rp = tile + tid * KC;
        const f32x4* R4 = (const f32x4*)Rlds;
        int sw = tid & 15;
        f32x4 a = {0.f, 0.f, 0.f, 0.f};
#pragma unroll
        for (int j = 0; j < 16; ++j)
            a += *(const f32x4*)(rp + ((j ^ sw) << 2)) * R4[j];
        sbuf[tid] = a[0] + a[1] + a[2] + a[3];
    }
    __syncthreads();

    // ---- phase 3: lane = k; 32 rows per wave ----
    float Rl = Rlds[lane];
    float wacc = 0.f;
    int rbase = wave * 32;
#pragma unroll 4
    for (int r = 0; r < 32; ++r) {
        int rr = rbase + r;
        int m = m0 + rr;
        float e = tile[rr * KC + (lane ^ ((rr & 15) << 2))];  // raw E_true[m][lane]
        float s = sbuf[rr];
        float cold = (MODE == 0) ? 1.0f : c[m];
        float cnew = cold / (fmaxf(cold * s, 1e-12f) * 65536.0f);
        if (MODE == 2) {
            float a = e * Rl * cnew * 65536.0f;
            size_t idx = (size_t)m * KC + lane;
            Aout[idx] = a;
            Qbf[idx] = f2bf(a * invn[m]);
            wacc += a;
        } else {
            if (lane == 0) c[m] = cnew;
            wacc += e * cnew;  // = sum_m E*c directly (no /R needed)
        }
    }
    bacc[wave][lane] = wacc;
    __syncthreads();
    if (tid < KC)  // group-atomic fold: 8 blocks/group
        atomicAdd(&PSGnext[(size_t)(blockIdx.x >> 3) * KC + tid],
                  bacc[0][tid] + bacc[1][tid] + bacc[2][tid] + bacc[3][tid]);
}

// ---------------- K3: weighted centers — bf16 MFMA GEMM, prefetched ---------------
__global__ __launch_bounds__(256) void k_weighted(const float* __restrict__ F,
                                                  const short* __restrict__ Qbf,
                                                  float* __restrict__ P) {
    __shared__ short ldsF[DT * MB];  // [d][m] swizzled, 16 KiB
    __shared__ short ldsQ[KC * MB];  // [k][m] swizzled, 8 KiB
    int tid = threadIdx.x;
    int dt = blockIdx.x;  // 0..5
    int ms = blockIdx.y;  // 0..MSEG-1
    int wave = tid >> 6, lane = tid & 63;
    int l15 = lane & 15, lhi = lane >> 4;

    int m0 = ms * (MB * CH);
    int d0 = dt * DT;

    f32x4 acc[4][2];
#pragma unroll
    for (int kt = 0; kt < 4; ++kt)
#pragma unroll
        for (int ds = 0; ds < 2; ++ds) acc[kt][ds] = (f32x4){0.f, 0.f, 0.f, 0.f};

    int f_dq = (tid & 31) * 4;        // d 0..124 (float4 loads)
    int f_m8 = (tid >> 5) * 8;        // m 0..56
    int q_kq = (tid & 15) * 4;        // k 0..60   (threads <128)
    int q_m8 = ((tid >> 4) & 7) * 8;  // m 0..56

    float4 rf[8];
    u16x4 q[8];
#define LOADCH(mb_)                                                                       \
    do {                                                                                  \
        _Pragma("unroll") for (int j = 0; j < 8; ++j)                                     \
            rf[j] = *(const float4*)(F + (size_t)((mb_) + f_m8 + j) * DIM + d0 + f_dq);   \
        if (tid < 128) {                                                                  \
            _Pragma("unroll") for (int j = 0; j < 8; ++j)                                 \
                q[j] = *(const u16x4*)(Qbf + (size_t)((mb_) + q_m8 + j) * KC + q_kq);     \
        }                                                                                 \
    } while (0)

    LOADCH(m0);
    for (int ch = 0; ch < CH; ++ch) {
        __syncthreads();  // previous chunk's LDS reads done before overwrite
#pragma unroll
        for (int i = 0; i < 4; ++i) {
            int d = f_dq + i;
            uint4 w;
            w.x = (unsigned)(unsigned short)f2bf(rf[0][i]) | ((unsigned)(unsigned short)f2bf(rf[1][i]) << 16);
            w.y = (unsigned)(unsigned short)f2bf(rf[2][i]) | ((unsigned)(unsigned short)f2bf(rf[3][i]) << 16);
            w.z = (unsigned)(unsigned short)f2bf(rf[4][i]) | ((unsigned)(unsigned short)f2bf(rf[5][i]) << 16);
            w.w = (unsigned)(unsigned short)f2bf(rf[6][i]) | ((unsigned)(unsigned short)f2bf(rf[7][i]) << 16);
            int byte = (d * (MB * 2) + f_m8 * 2) ^ ((d & 7) << 4);
            *(uint4*)((char*)ldsF + byte) = w;
        }
        if (tid < 128) {
#pragma unroll
            for (int i = 0; i < 4; ++i) {
                int k = q_kq + i;
                uint4 w;
                w.x = (unsigned)q[0][i] | ((unsigned)q[1][i] << 16);
                w.y = (unsigned)q[2][i] | ((unsigned)q[3][i] << 16);
                w.z = (unsigned)q[4][i] | ((unsigned)q[5][i] << 16);
                w.w = (unsigned)q[6][i] | ((unsigned)q[7][i] << 16);
                int byte = (k * (MB * 2) + q_m8 * 2) ^ ((k & 7) << 4);
                *(uint4*)((char*)ldsQ + byte) = w;
            }
        }
        __syncthreads();
        if (ch + 1 < CH) LOADCH(m0 + (ch + 1) * MB);  // prefetch overlaps MFMA below
#pragma unroll
        for (int h = 0; h < 2; ++h) {
            bf16x8 afr[4];
#pragma unroll
            for (int kt = 0; kt < 4; ++kt) {
                int k = kt * 16 + l15;
                int byte = (k * (MB * 2) + (h * 32 + lhi * 8) * 2) ^ ((k & 7) << 4);
                afr[kt] = *(bf16x8*)((char*)ldsQ + byte);
            }
#pragma unroll
            for (int ds = 0; ds < 2; ++ds) {
                int d = wave * 32 + ds * 16 + l15;
                int byte = (d * (MB * 2) + (h * 32 + lhi * 8) * 2) ^ ((d & 7) << 4);
                bf16x8 bfr = *(bf16x8*)((char*)ldsF + byte);
#pragma unroll
                for (int kt = 0; kt < 4; ++kt)
                    acc[kt][ds] = __builtin_amdgcn_mfma_f32_16x16x32_bf16(afr[kt], bfr, acc[kt][ds], 0, 0, 0);
            }
        }
    }
#undef LOADCH

    float* Pb = P + (size_t)ms * (KC * DIM) + d0;
#pragma unroll
    for (int kt = 0; kt < 4; ++kt)
#pragma unroll
        for (int ds = 0; ds < 2; ++ds) {
            int d = wave * 32 + ds * 16 + l15;
#pragma unroll
            for (int r4 = 0; r4 < 4; ++r4) {
                int k = kt * 16 + lhi * 4 + r4;
                Pb[(size_t)k * DIM + d] = acc[kt][ds][r4];
            }
        }
}

// ---------------- K4: partial-reduce + mass-reduce + finalize centers -------------
__global__ __launch_bounds__(256) void k_final(const float* __restrict__ P,
                                               const float* __restrict__ PSGM,
                                               const float* __restrict__ cn,
                                               float* __restrict__ outC) {
    int k = blockIdx.x, tid = threadIdx.x;
    __shared__ float red[4];

    float msum = (tid < PSG_ROWS) ? PSGM[(size_t)tid * KC + k] : 0.f;
    for (int o = 32; o; o >>= 1) msum += __shfl_xor(msum, o);
    if ((tid & 63) == 0) red[tid >> 6] = msum;
    __syncthreads();
    float mk = fmaxf(red[0] + red[1] + red[2] + red[3], 1e-6f);
    __syncthreads();

    float w[3];
#pragma unroll
    for (int g = 0; g < 3; ++g) {
        int d = tid + g * 256;
        const float* pp = P + (size_t)k * DIM + d;
        float s0 = 0.f, s1 = 0.f, s2 = 0.f, s3 = 0.f;
        size_t stride = (size_t)KC * DIM;
#pragma unroll 4
        for (int msg = 0; msg < MSEG; msg += 4) {
            s0 += pp[(size_t)msg * stride];
            s1 += pp[(size_t)(msg + 1) * stride];
            s2 += pp[(size_t)(msg + 2) * stride];
            s3 += pp[(size_t)(msg + 3) * stride];
        }
        w[g] = ((s0 + s1) + (s2 + s3)) / mk;
    }

    float ss = w[0] * w[0] + w[1] * w[1] + w[2] * w[2];
    for (int o = 32; o; o >>= 1) ss += __shfl_xor(ss, o);
    if ((tid & 63) == 0) red[tid >> 6] = ss;
    __syncthreads();
    ss = red[0] + red[1] + red[2] + red[3];
    float n1 = fmaxf(sqrtf(ss), 1e-12f);
    __syncthreads();

    float u0 = 0.99f * cn[k * DIM + tid]       + 0.01f * (w[0] / n1);
    float u1 = 0.99f * cn[k * DIM + tid + 256] + 0.01f * (w[1] / n1);
    float u2 = 0.99f * cn[k * DIM + tid + 512] + 0.01f * (w[2] / n1);
    float ss2 = u0 * u0 + u1 * u1 + u2 * u2;
    for (int o = 32; o; o >>= 1) ss2 += __shfl_xor(ss2, o);
    if ((tid & 63) == 0) red[tid >> 6] = ss2;
    __syncthreads();
    ss2 = red[0] + red[1] + red[2] + red[3];
    float n2 = fmaxf(sqrtf(ss2), 1e-12f);

    outC[k * DIM + tid]       = u0 / n2;
    outC[k * DIM + tid + 256] = u1 / n2;
    outC[k * DIM + tid + 512] = u2 / n2;
}

extern "C" void kernel_launch(void* const* d_in, const int* in_sizes, int n_in,
                              void* d_out, int out_size, void* d_ws, size_t ws_size,
                              hipStream_t stream) {
    const float* F = (const float*)d_in[0];        // [65536][768]
    const float* centers = (const float*)d_in[1];  // [64][768]
    float* out = (float*)d_out;
    float* A = out;                                 // assignments [65536][64]
    float* outC = out + (size_t)M_TOTAL * KC;       // updated centers [64][768]

    float* w = (float*)d_ws;                        // ws = 768 MiB
    float* cn   = w;                                // 49152
    short* cnbf = (short*)(w + 49152);              // 24576 float slots
    float* R0   = w + 73728;                        // 64
    float* R1   = w + 73792;                        // 64
    float* invn = w + 74048;                        // 65536
    float* cbuf = w + 139584;                       // 65536
    float* E    = w + 205120;                       // 4194304 (pre-swizzled layout)
    short* Qbf  = (short*)(w + 4399424);            // 2097152 float slots (8 MiB)
    float* PSG  = w + 6496576;                      // 4 x [64][64] = 16384 floats
    float* PSG0 = PSG;
    float* PSG1 = PSG + 4096;
    float* PSG2 = PSG + 8192;
    float* PSGM = PSG + 12288;
    float* partial = w + 6520000;                   // MSEG*64*768 = 6291456 (24 MiB)

    k_centers<<<KC, 256, 0, stream>>>(centers, cn, cnbf, PSG);
    k_logits<<<LOGITS_BLOCKS, 256, 0, stream>>>(F, cnbf, E, invn, PSG0);
    k_sink<0><<<SINK_BLOCKS, 256, 0, stream>>>(E, nullptr, PSG0, invn, cbuf, PSG1, R0, A, Qbf);
    k_sink<1><<<SINK_BLOCKS, 256, 0, stream>>>(E, R0, PSG1, invn, cbuf, PSG2, R1, A, Qbf);
    k_sink<2><<<SINK_BLOCKS, 256, 0, stream>>>(E, R1, PSG2, invn, cbuf, PSGM, nullptr, A, Qbf);

    dim3 wgrid(DIM / DT, MSEG);
    k_weighted<<<wgrid, 256, 0, stream>>>(F, Qbf, partial);
    k_final<<<KC, 256, 0, stream>>>(partial, PSGM, cn, outC);
}